// Round 2
// baseline (6908.027 us; speedup 1.0000x reference)
//
#include <hip/hip_runtime.h>
#include <math.h>

// Problem dims
#define Bb 256
#define Nn 196
#define Dd 512
#define Hh 102
#define Kk 64
#define Mm 40

// ws layout: logits [B][2][N][K] f32 = 25,690,112 B ; aggP [2][B][K][D] f32 = 67,108,864 B
#define LOGITS_BYTES 25690112

__device__ __forceinline__ float dot4(const float4 a, const float4 b) {
  return a.x*b.x + a.y*b.y + a.z*b.z + a.w*b.w;
}

__device__ __forceinline__ float wave_reduce_sum(float v) {
#pragma unroll
  for (int o = 1; o < 64; o <<= 1) v += __shfl_xor(v, o, 64);
  return v;
}

// ---------------------------------------------------------------------------
// K1: per 112-token tile of one (b, path): LN -> gelu(x@w1+b1) -> @w2+b2
// 512 threads. Phase1 tile: 7 tok x 4 hid per thread (acc=28 regs, no spill).
// ---------------------------------------------------------------------------
__global__ __launch_bounds__(512, 4) void k1_logits(
    const float* __restrict__ x_s, const float* __restrict__ x_d,
    const float* __restrict__ g_s, const float* __restrict__ bb_s,
    const float* __restrict__ w1_s, const float* __restrict__ b1_s,
    const float* __restrict__ w2_s, const float* __restrict__ b2_s,
    const float* __restrict__ g_d, const float* __restrict__ bb_d,
    const float* __restrict__ w1_d, const float* __restrict__ b1_d,
    const float* __restrict__ w2_d, const float* __restrict__ b2_d,
    float* __restrict__ logits)
{
  // phase1: gs(512) bs(512) st(224) xs(112x36) w1t(128x36) = 9888 f = 39.5 KB
  // phase2: hs(112x108) w2t(32x108) = 15552 f = 62.2 KB  (union)
  __shared__ __align__(16) float smem[15552];
  float* gs  = smem;          // 512
  float* bs  = smem + 512;    // 512
  float* st  = smem + 1024;   // [112][2] mu, rstd
  float* xs  = smem + 1248;   // [112][36]
  float* w1t = smem + 5280;   // [128][36]
  float* hs  = smem;          // [112][108]  stride 108 == 12 mod 32: conflict-free
  float* w2t = smem + 12096;  // [32][108]

  const int tid = threadIdx.x;
  const int ntile = blockIdx.x, p = blockIdx.y, b = blockIdx.z;
  const int nbase = ntile * 112;
  const float* x  = p ? x_d  : x_s;
  const float* gp = p ? g_d  : g_s;
  const float* bp = p ? bb_d : bb_s;
  const float* w1 = p ? w1_d : w1_s;
  const float* b1 = p ? b1_d : b1_s;
  const float* w2 = p ? w2_d : w2_s;
  const float* b2 = p ? b2_d : b2_s;

  gs[tid] = gp[tid];
  bs[tid] = bp[tid];

  // LN stats: wave per token
  const int wv = tid >> 6, lane = tid & 63;
  for (int i = 0; i < 14; ++i) {
    const int t = wv + 8 * i;
    const int n = nbase + t;
    float s = 0.f, ss = 0.f;
    if (n < Nn) {
      const float* xr = x + ((size_t)(b * Nn + n)) * Dd;
      float4 a = *(const float4*)(xr + lane * 4);
      float4 c = *(const float4*)(xr + 256 + lane * 4);
      s  = a.x + a.y + a.z + a.w + c.x + c.y + c.z + c.w;
      ss = dot4(a, a) + dot4(c, c);
    }
    s = wave_reduce_sum(s); ss = wave_reduce_sum(ss);
    if (lane == 0) {
      float mu  = s * (1.f / 512.f);
      float var = fmaxf(ss * (1.f / 512.f) - mu * mu, 0.f);
      st[2 * t]     = mu;
      st[2 * t + 1] = (n < Nn) ? rsqrtf(var + 1e-5f) : 0.f;
    }
  }
  __syncthreads();

  // h-GEMM: thread (ti 0..15, ji 0..31): t = ti+16l (l<7), j = ji+32m (m<4)
  const int ti = tid & 15, ji = tid >> 4;
  float acc[7][4];
#pragma unroll
  for (int l = 0; l < 7; ++l)
#pragma unroll
    for (int m = 0; m < 4; ++m) acc[l][m] = 0.f;

  for (int ch = 0; ch < 16; ++ch) {
    const int c0 = ch * 32;
    __syncthreads();
    // stage w1 chunk transposed: w1t[j][cl]
    for (int idx = tid; idx < 3264; idx += 512) {
      int cl = idx / 102;
      int j  = idx - cl * 102;
      w1t[j * 36 + cl] = w1[(size_t)(c0 + cl) * Hh + j];
    }
    for (int idx = tid; idx < 936; idx += 512) {
      int j  = 102 + idx / 36;
      int cl = idx - (idx / 36) * 36;
      w1t[j * 36 + cl] = 0.f;
    }
    // stage x chunk with LN applied
    for (int idx = tid; idx < 896; idx += 512) {
      int t = idx >> 3, cf = idx & 7;
      int n = nbase + t;
      float mu = st[2 * t], rs = st[2 * t + 1];
      float4 v = {0.f, 0.f, 0.f, 0.f};
      if (n < Nn) v = *(const float4*)(x + ((size_t)(b * Nn + n)) * Dd + c0 + cf * 4);
      int c = c0 + cf * 4;
      float4 o;
      o.x = (v.x - mu) * rs * gs[c]     + bs[c];
      o.y = (v.y - mu) * rs * gs[c + 1] + bs[c + 1];
      o.z = (v.z - mu) * rs * gs[c + 2] + bs[c + 2];
      o.w = (v.w - mu) * rs * gs[c + 3] + bs[c + 3];
      *(float4*)(xs + t * 36 + cf * 4) = o;
    }
    __syncthreads();
#pragma unroll
    for (int cq = 0; cq < 8; ++cq) {
      float4 xq[7], wq[4];
#pragma unroll
      for (int l = 0; l < 7; ++l) xq[l] = *(const float4*)(xs + (ti + 16 * l) * 36 + cq * 4);
#pragma unroll
      for (int m = 0; m < 4; ++m) wq[m] = *(const float4*)(w1t + (ji + 32 * m) * 36 + cq * 4);
#pragma unroll
      for (int l = 0; l < 7; ++l)
#pragma unroll
        for (int m = 0; m < 4; ++m)
          acc[l][m] += dot4(xq[l], wq[m]);
    }
  }

  // bias + exact gelu -> hs (union flip)
  float b1r[4];
#pragma unroll
  for (int m = 0; m < 4; ++m) {
    int j = ji + 32 * m;
    b1r[m] = (j < Hh) ? b1[j] : 0.f;
  }
  __syncthreads();
#pragma unroll
  for (int l = 0; l < 7; ++l) {
    int t = ti + 16 * l;
#pragma unroll
    for (int m = 0; m < 4; ++m) {
      int j = ji + 32 * m;
      if (j < 104) {
        float z = acc[l][m] + b1r[m];
        hs[t * 108 + j] = 0.5f * z * (1.f + erff(z * 0.70710678118f));
      }
    }
  }

  // logits GEMM, two k-halves of 32. thread (ki 0..7, ti2 0..63): k = half*32+kk*8+ki
  const int ki = tid & 7, ti2 = tid >> 3;
  for (int half = 0; half < 2; ++half) {
    __syncthreads();
    for (int idx = tid; idx < 3264; idx += 512) {
      int j = idx >> 5, ko = idx & 31;
      w2t[ko * 108 + j] = w2[(size_t)j * Kk + half * 32 + ko];
    }
    for (int idx = tid; idx < 192; idx += 512) {
      int ko = idx / 6, jp = 102 + (idx - (idx / 6) * 6);
      w2t[ko * 108 + jp] = 0.f;
    }
    __syncthreads();
    float acc2[2][4];
#pragma unroll
    for (int l = 0; l < 2; ++l)
#pragma unroll
      for (int kk = 0; kk < 4; ++kk) acc2[l][kk] = 0.f;
    int tcl[2];
    tcl[0] = ti2;
    tcl[1] = min(ti2 + 64, 111);
#pragma unroll
    for (int jq = 0; jq < 26; ++jq) {
      float4 hq[2], wq2[4];
#pragma unroll
      for (int l = 0; l < 2; ++l)   hq[l]   = *(const float4*)(hs + tcl[l] * 108 + jq * 4);
#pragma unroll
      for (int kk = 0; kk < 4; ++kk) wq2[kk] = *(const float4*)(w2t + (kk * 8 + ki) * 108 + jq * 4);
#pragma unroll
      for (int l = 0; l < 2; ++l)
#pragma unroll
        for (int kk = 0; kk < 4; ++kk)
          acc2[l][kk] += dot4(hq[l], wq2[kk]);
    }
#pragma unroll
    for (int l = 0; l < 2; ++l) {
      int t = ti2 + 64 * l, n = nbase + t;
      if (t < 112 && n < Nn) {
#pragma unroll
        for (int kk = 0; kk < 4; ++kk) {
          int k = half * 32 + kk * 8 + ki;
          logits[((size_t)(b * 2 + p) * Nn + n) * Kk + k] = acc2[l][kk] + b2[k];
        }
      }
    }
  }
}

// ---------------------------------------------------------------------------
// K2: per (p, b): softmax over n (scale pre-applied), then agg = w @ x
// ---------------------------------------------------------------------------
__global__ __launch_bounds__(512) void k2_softmax_agg(
    const float* __restrict__ x_s, const float* __restrict__ x_d,
    const float* __restrict__ logits, const float* __restrict__ scale,
    float* __restrict__ aggP)
{
  __shared__ __align__(16) float wt[196 * 68];   // [n][k] padded
  __shared__ __align__(16) float xt[4 * 512];
  __shared__ float red[8 * 64];
  __shared__ float mxk[64];
  __shared__ float rsk[64];
  const int tid = threadIdx.x;
  const int p = blockIdx.x, b = blockIdx.y;
  const float* x = p ? x_d : x_s;
  const float sc = scale[0];
  const float* lg = logits + (size_t)(b * 2 + p) * Nn * Kk;
  for (int idx = tid; idx < Nn * Kk; idx += 512) {
    int n = idx >> 6, k = idx & 63;
    wt[n * 68 + k] = lg[idx] * sc;
  }
  __syncthreads();
  const int k = tid & 63, g = tid >> 6;
  float mloc = -1e30f;
  for (int n = g; n < Nn; n += 8) mloc = fmaxf(mloc, wt[n * 68 + k]);
  red[g * 64 + k] = mloc;
  __syncthreads();
  if (g == 0) {
    float mm = red[k];
#pragma unroll
    for (int gg = 1; gg < 8; ++gg) mm = fmaxf(mm, red[gg * 64 + k]);
    mxk[k] = mm;
  }
  __syncthreads();
  const float mk = mxk[k];
  float sloc = 0.f;
  for (int n = g; n < Nn; n += 8) {
    float e = expf(wt[n * 68 + k] - mk);
    wt[n * 68 + k] = e;
    sloc += e;
  }
  red[g * 64 + k] = sloc;
  __syncthreads();
  if (g == 0) {
    float sm = red[k];
#pragma unroll
    for (int gg = 1; gg < 8; ++gg) sm += red[gg * 64 + k];
    rsk[k] = 1.f / sm;
  }
  __syncthreads();
  const float rk = rsk[k];
  for (int n = g; n < Nn; n += 8) wt[n * 68 + k] *= rk;

  // agg: wave kg owns k = kg*8+kk; lane cg owns c = cg*4 + 256q
  const int kg = tid >> 6, cg = tid & 63;
  float acc[8][8];
#pragma unroll
  for (int kk = 0; kk < 8; ++kk)
#pragma unroll
    for (int e = 0; e < 8; ++e) acc[kk][e] = 0.f;

  for (int nt = 0; nt < 49; ++nt) {
    const int n0 = nt * 4;
    __syncthreads();   // also orders softmax writes before first agg reads
    {
      int row = tid >> 7, cf = tid & 127;
      float4 v = *(const float4*)(x + ((size_t)(b * Nn + n0 + row)) * Dd + cf * 4);
      *(float4*)(xt + row * 512 + cf * 4) = v;
    }
    __syncthreads();
#pragma unroll
    for (int i = 0; i < 4; ++i) {
      const int n = n0 + i;
      float4 wa = *(const float4*)(wt + n * 68 + kg * 8);
      float4 wb = *(const float4*)(wt + n * 68 + kg * 8 + 4);
      float4 xa = *(const float4*)(xt + i * 512 + cg * 4);
      float4 xb = *(const float4*)(xt + i * 512 + 256 + cg * 4);
      float wv8[8] = {wa.x, wa.y, wa.z, wa.w, wb.x, wb.y, wb.z, wb.w};
      float xv8[8] = {xa.x, xa.y, xa.z, xa.w, xb.x, xb.y, xb.z, xb.w};
#pragma unroll
      for (int kk = 0; kk < 8; ++kk)
#pragma unroll
        for (int e = 0; e < 8; ++e)
          acc[kk][e] += wv8[kk] * xv8[e];
    }
  }
#pragma unroll
  for (int kk = 0; kk < 8; ++kk) {
    size_t base = ((size_t)((p * Bb + b) * Kk + kg * 8 + kk)) * Dd;
    float4 o0 = {acc[kk][0], acc[kk][1], acc[kk][2], acc[kk][3]};
    float4 o1 = {acc[kk][4], acc[kk][5], acc[kk][6], acc[kk][7]};
    *(float4*)(aggP + base + cg * 4) = o0;
    *(float4*)(aggP + base + 256 + cg * 4) = o1;
  }
}

// ---------------------------------------------------------------------------
// K4: per b: v = l2norm(agg_s+agg_d), t = l2norm(words), sim -> leaky -> pools
// ---------------------------------------------------------------------------
__global__ __launch_bounds__(256) void k4_final(
    const float* __restrict__ words, const float* __restrict__ aggP,
    float* __restrict__ outp)
{
  __shared__ __align__(16) float vsm[16 * 512];
  __shared__ float rnv[16];
  __shared__ float colp[4 * 64];
  __shared__ float rowm[40];
  const int tid = threadIdx.x, b = blockIdx.x;
  const int w = tid >> 6, lane = tid & 63;
  const float* a0 = aggP + (size_t)b * Kk * Dd;
  const float* a1 = aggP + ((size_t)(Bb + b)) * Kk * Dd;
  if (tid < 40) rowm[tid] = -1e30f;
  float cm = -1e30f;

  for (int kc = 0; kc < 4; ++kc) {
    __syncthreads();
    for (int idx = tid; idx < 2048; idx += 256) {
      int r = idx >> 7, cf = idx & 127;
      size_t off = ((size_t)(kc * 16 + r)) * Dd + cf * 4;
      float4 u = *(const float4*)(a0 + off);
      float4 v = *(const float4*)(a1 + off);
      float4 s4 = {u.x + v.x, u.y + v.y, u.z + v.z, u.w + v.w};
      *(float4*)(vsm + r * 512 + cf * 4) = s4;
    }
    __syncthreads();
#pragma unroll
    for (int i = 0; i < 4; ++i) {
      int r = w * 4 + i;
      float4 aq = *(const float4*)(vsm + r * 512 + lane * 4);
      float4 bq = *(const float4*)(vsm + r * 512 + 256 + lane * 4);
      float ss = wave_reduce_sum(dot4(aq, aq) + dot4(bq, bq));
      if (lane == 0) rnv[r] = 1.f / fmaxf(sqrtf(ss), 1e-8f);
    }
    __syncthreads();
    for (int i = 0; i < 10; ++i) {
      const int m = w + 4 * i;
      const float* tr = words + ((size_t)(b * Mm + m)) * Dd;
      float4 ta = *(const float4*)(tr + lane * 4);
      float4 tb = *(const float4*)(tr + 256 + lane * 4);
      float ss = wave_reduce_sum(dot4(ta, ta) + dot4(tb, tb));
      float rnt = 1.f / fmaxf(sqrtf(ss), 1e-8f);
      float rmax_loc = -1e30f;
#pragma unroll
      for (int kk = 0; kk < 16; ++kk) {
        float4 va = *(const float4*)(vsm + kk * 512 + lane * 4);
        float4 vb = *(const float4*)(vsm + kk * 512 + 256 + lane * 4);
        float d = wave_reduce_sum(dot4(ta, va) + dot4(tb, vb));
        float s = d * rnt * rnv[kk];
        s = (s >= 0.f) ? s : 0.1f * s;
        rmax_loc = fmaxf(rmax_loc, s);
        if (lane == (kc * 16 + kk)) cm = fmaxf(cm, s);
      }
      if (lane == 0) rowm[m] = fmaxf(rowm[m], rmax_loc);
    }
  }
  colp[w * 64 + lane] = cm;
  __syncthreads();
  if (w == 0) {
    float c2 = fmaxf(fmaxf(colp[lane], colp[64 + lane]),
                     fmaxf(colp[128 + lane], colp[192 + lane]));
    float csum = wave_reduce_sum(c2);
    float rv = (lane < 40) ? rowm[lane] : 0.f;
    float rsum = wave_reduce_sum(rv);
    if (lane == 0) outp[b] = rsum * (1.f / 40.f) + csum * (1.f / 64.f);
  }
}

extern "C" void kernel_launch(void* const* d_in, const int* in_sizes, int n_in,
                              void* d_out, int out_size, void* d_ws, size_t ws_size,
                              hipStream_t stream)
{
  const float* x_s   = (const float*)d_in[0];
  const float* x_d   = (const float*)d_in[1];
  const float* words = (const float*)d_in[2];
  const float* g_s   = (const float*)d_in[3];
  const float* b_s   = (const float*)d_in[4];
  const float* w1_s  = (const float*)d_in[5];
  const float* b1_s  = (const float*)d_in[6];
  const float* w2_s  = (const float*)d_in[7];
  const float* b2_s  = (const float*)d_in[8];
  const float* g_d   = (const float*)d_in[9];
  const float* b_d   = (const float*)d_in[10];
  const float* w1_d  = (const float*)d_in[11];
  const float* b1_d  = (const float*)d_in[12];
  const float* w2_d  = (const float*)d_in[13];
  const float* b2_d  = (const float*)d_in[14];
  const float* scale = (const float*)d_in[15];
  (void)in_sizes; (void)n_in; (void)out_size; (void)ws_size;

  float* logits = (float*)d_ws;
  float* aggP   = (float*)((char*)d_ws + LOGITS_BYTES);

  hipLaunchKernelGGL(k1_logits, dim3(2, 2, 256), dim3(512), 0, stream,
                     x_s, x_d, g_s, b_s, w1_s, b1_s, w2_s, b2_s,
                     g_d, b_d, w1_d, b1_d, w2_d, b2_d, logits);
  hipLaunchKernelGGL(k2_softmax_agg, dim3(2, 256), dim3(512), 0, stream,
                     x_s, x_d, logits, scale, aggP);
  hipLaunchKernelGGL(k4_final, dim3(256), dim3(256), 0, stream,
                     words, aggP, (float*)d_out);
}

// Round 3
// 3306.642 us; speedup vs baseline: 2.0891x; 2.0891x over previous
//
#include <hip/hip_runtime.h>
#include <math.h>

// Problem dims
#define Bb 256
#define Nn 196
#define Dd 512
#define Hh 102
#define Kk 64
#define Mm 40

// ws layout: logits [B][2][N][K] f32 = 25,690,112 B ; aggP [2][B][K][D] f32 = 67,108,864 B
#define LOGITS_BYTES 25690112

__device__ __forceinline__ float dot4(const float4 a, const float4 b) {
  return a.x*b.x + a.y*b.y + a.z*b.z + a.w*b.w;
}

__device__ __forceinline__ float wave_reduce_sum(float v) {
#pragma unroll
  for (int o = 1; o < 64; o <<= 1) v += __shfl_xor(v, o, 64);
  return v;
}

// ---------------------------------------------------------------------------
// K1: per 112-token tile of one (b, path): LN -> gelu(x@w1+b1) -> @w2+b2
// 512 threads, launch_bounds(512,2): VGPR cap 256, allocator has room.
// Inner-loop live set ~48 floats (acc 28 + wq 16 + xq 4) -> no spill.
// ---------------------------------------------------------------------------
__global__ __launch_bounds__(512, 2) void k1_logits(
    const float* __restrict__ x_s, const float* __restrict__ x_d,
    const float* __restrict__ g_s, const float* __restrict__ bb_s,
    const float* __restrict__ w1_s, const float* __restrict__ b1_s,
    const float* __restrict__ w2_s, const float* __restrict__ b2_s,
    const float* __restrict__ g_d, const float* __restrict__ bb_d,
    const float* __restrict__ w1_d, const float* __restrict__ b1_d,
    const float* __restrict__ w2_d, const float* __restrict__ b2_d,
    float* __restrict__ logits)
{
  // phase1: gs(512) bs(512) st(224) xs(112x36) w1t(128x36) = 9888 f = 39.5 KB
  // phase2: hs(112x108) w2t(32x108) = 15552 f = 62.2 KB  (union)
  __shared__ __align__(16) float smem[15552];
  float* gs  = smem;          // 512
  float* bs  = smem + 512;    // 512
  float* st  = smem + 1024;   // [112][2] mu, rstd
  float* xs  = smem + 1248;   // [112][36]
  float* w1t = smem + 5280;   // [128][36]
  float* hs  = smem;          // [112][108]  stride 108 == 12 mod 32: conflict-free
  float* w2t = smem + 12096;  // [32][108]

  const int tid = threadIdx.x;
  const int ntile = blockIdx.x, p = blockIdx.y, b = blockIdx.z;
  const int nbase = ntile * 112;
  const float* x  = p ? x_d  : x_s;
  const float* gp = p ? g_d  : g_s;
  const float* bp = p ? bb_d : bb_s;
  const float* w1 = p ? w1_d : w1_s;
  const float* b1 = p ? b1_d : b1_s;
  const float* w2 = p ? w2_d : w2_s;
  const float* b2 = p ? b2_d : b2_s;

  gs[tid] = gp[tid];
  bs[tid] = bp[tid];

  // LN stats: wave per token
  const int wv = tid >> 6, lane = tid & 63;
  for (int i = 0; i < 14; ++i) {
    const int t = wv + 8 * i;
    const int n = nbase + t;
    float s = 0.f, ss = 0.f;
    if (n < Nn) {
      const float* xr = x + ((size_t)(b * Nn + n)) * Dd;
      float4 a = *(const float4*)(xr + lane * 4);
      float4 c = *(const float4*)(xr + 256 + lane * 4);
      s  = a.x + a.y + a.z + a.w + c.x + c.y + c.z + c.w;
      ss = dot4(a, a) + dot4(c, c);
    }
    s = wave_reduce_sum(s); ss = wave_reduce_sum(ss);
    if (lane == 0) {
      float mu  = s * (1.f / 512.f);
      float var = fmaxf(ss * (1.f / 512.f) - mu * mu, 0.f);
      st[2 * t]     = mu;
      st[2 * t + 1] = (n < Nn) ? rsqrtf(var + 1e-5f) : 0.f;
    }
  }
  __syncthreads();

  // h-GEMM: thread (ti 0..15, ji 0..31): t = ti+16l (l<7), j = ji+32m (m<4)
  const int ti = tid & 15, ji = tid >> 4;
  float acc[7][4];
#pragma unroll
  for (int l = 0; l < 7; ++l)
#pragma unroll
    for (int m = 0; m < 4; ++m) acc[l][m] = 0.f;

  for (int ch = 0; ch < 16; ++ch) {
    const int c0 = ch * 32;
    __syncthreads();
    // stage w1 chunk transposed: w1t[j][cl]
    for (int idx = tid; idx < 3264; idx += 512) {
      int cl = idx / 102;
      int j  = idx - cl * 102;
      w1t[j * 36 + cl] = w1[(size_t)(c0 + cl) * Hh + j];
    }
    for (int idx = tid; idx < 936; idx += 512) {
      int j  = 102 + idx / 36;
      int cl = idx - (idx / 36) * 36;
      w1t[j * 36 + cl] = 0.f;
    }
    // stage x chunk with LN applied
    for (int idx = tid; idx < 896; idx += 512) {
      int t = idx >> 3, cf = idx & 7;
      int n = nbase + t;
      float mu = st[2 * t], rs = st[2 * t + 1];
      float4 v = {0.f, 0.f, 0.f, 0.f};
      if (n < Nn) v = *(const float4*)(x + ((size_t)(b * Nn + n)) * Dd + c0 + cf * 4);
      int c = c0 + cf * 4;
      float4 o;
      o.x = (v.x - mu) * rs * gs[c]     + bs[c];
      o.y = (v.y - mu) * rs * gs[c + 1] + bs[c + 1];
      o.z = (v.z - mu) * rs * gs[c + 2] + bs[c + 2];
      o.w = (v.w - mu) * rs * gs[c + 3] + bs[c + 3];
      *(float4*)(xs + t * 36 + cf * 4) = o;
    }
    __syncthreads();
#pragma unroll
    for (int cq = 0; cq < 8; ++cq) {
      float4 wq[4];
#pragma unroll
      for (int m = 0; m < 4; ++m) wq[m] = *(const float4*)(w1t + (ji + 32 * m) * 36 + cq * 4);
#pragma unroll
      for (int l = 0; l < 7; ++l) {
        float4 xq = *(const float4*)(xs + (ti + 16 * l) * 36 + cq * 4);
#pragma unroll
        for (int m = 0; m < 4; ++m)
          acc[l][m] += dot4(xq, wq[m]);
      }
    }
  }

  // bias + exact gelu -> hs (union flip)
  float b1r[4];
#pragma unroll
  for (int m = 0; m < 4; ++m) {
    int j = ji + 32 * m;
    b1r[m] = (j < Hh) ? b1[j] : 0.f;
  }
  __syncthreads();
#pragma unroll
  for (int l = 0; l < 7; ++l) {
    int t = ti + 16 * l;
#pragma unroll
    for (int m = 0; m < 4; ++m) {
      int j = ji + 32 * m;
      if (j < 104) {
        float z = acc[l][m] + b1r[m];
        hs[t * 108 + j] = 0.5f * z * (1.f + erff(z * 0.70710678118f));
      }
    }
  }

  // logits GEMM, two k-halves of 32. thread (ki 0..7, ti2 0..63): k = half*32+kk*8+ki
  const int ki = tid & 7, ti2 = tid >> 3;
  for (int half = 0; half < 2; ++half) {
    __syncthreads();
    for (int idx = tid; idx < 3264; idx += 512) {
      int j = idx >> 5, ko = idx & 31;
      w2t[ko * 108 + j] = w2[(size_t)j * Kk + half * 32 + ko];
    }
    for (int idx = tid; idx < 192; idx += 512) {
      int ko = idx / 6, jp = 102 + (idx - (idx / 6) * 6);
      w2t[ko * 108 + jp] = 0.f;
    }
    __syncthreads();
    float acc2[2][4];
#pragma unroll
    for (int l = 0; l < 2; ++l)
#pragma unroll
      for (int kk = 0; kk < 4; ++kk) acc2[l][kk] = 0.f;
    int tcl[2];
    tcl[0] = ti2;
    tcl[1] = min(ti2 + 64, 111);
#pragma unroll
    for (int jq = 0; jq < 26; ++jq) {
      float4 wq2[4];
#pragma unroll
      for (int kk = 0; kk < 4; ++kk) wq2[kk] = *(const float4*)(w2t + (kk * 8 + ki) * 108 + jq * 4);
#pragma unroll
      for (int l = 0; l < 2; ++l) {
        float4 hq = *(const float4*)(hs + tcl[l] * 108 + jq * 4);
#pragma unroll
        for (int kk = 0; kk < 4; ++kk)
          acc2[l][kk] += dot4(hq, wq2[kk]);
      }
    }
#pragma unroll
    for (int l = 0; l < 2; ++l) {
      int t = ti2 + 64 * l, n = nbase + t;
      if (t < 112 && n < Nn) {
#pragma unroll
        for (int kk = 0; kk < 4; ++kk) {
          int k = half * 32 + kk * 8 + ki;
          logits[((size_t)(b * 2 + p) * Nn + n) * Kk + k] = acc2[l][kk] + b2[k];
        }
      }
    }
  }
}

// ---------------------------------------------------------------------------
// K2: per (p, b): softmax over n (scale pre-applied), then agg = w @ x
// ---------------------------------------------------------------------------
__global__ __launch_bounds__(512) void k2_softmax_agg(
    const float* __restrict__ x_s, const float* __restrict__ x_d,
    const float* __restrict__ logits, const float* __restrict__ scale,
    float* __restrict__ aggP)
{
  __shared__ __align__(16) float wt[196 * 68];   // [n][k] padded
  __shared__ __align__(16) float xt[4 * 512];
  __shared__ float red[8 * 64];
  __shared__ float mxk[64];
  __shared__ float rsk[64];
  const int tid = threadIdx.x;
  const int p = blockIdx.x, b = blockIdx.y;
  const float* x = p ? x_d : x_s;
  const float sc = scale[0];
  const float* lg = logits + (size_t)(b * 2 + p) * Nn * Kk;
  for (int idx = tid; idx < Nn * Kk; idx += 512) {
    int n = idx >> 6, k = idx & 63;
    wt[n * 68 + k] = lg[idx] * sc;
  }
  __syncthreads();
  const int k = tid & 63, g = tid >> 6;
  float mloc = -1e30f;
  for (int n = g; n < Nn; n += 8) mloc = fmaxf(mloc, wt[n * 68 + k]);
  red[g * 64 + k] = mloc;
  __syncthreads();
  if (g == 0) {
    float mm = red[k];
#pragma unroll
    for (int gg = 1; gg < 8; ++gg) mm = fmaxf(mm, red[gg * 64 + k]);
    mxk[k] = mm;
  }
  __syncthreads();
  const float mk = mxk[k];
  float sloc = 0.f;
  for (int n = g; n < Nn; n += 8) {
    float e = expf(wt[n * 68 + k] - mk);
    wt[n * 68 + k] = e;
    sloc += e;
  }
  red[g * 64 + k] = sloc;
  __syncthreads();
  if (g == 0) {
    float sm = red[k];
#pragma unroll
    for (int gg = 1; gg < 8; ++gg) sm += red[gg * 64 + k];
    rsk[k] = 1.f / sm;
  }
  __syncthreads();
  const float rk = rsk[k];
  for (int n = g; n < Nn; n += 8) wt[n * 68 + k] *= rk;

  // agg: wave kg owns k = kg*8+kk; lane cg owns c = cg*4 + 256q
  const int kg = tid >> 6, cg = tid & 63;
  float acc[8][8];
#pragma unroll
  for (int kk = 0; kk < 8; ++kk)
#pragma unroll
    for (int e = 0; e < 8; ++e) acc[kk][e] = 0.f;

  for (int nt = 0; nt < 49; ++nt) {
    const int n0 = nt * 4;
    __syncthreads();   // also orders softmax writes before first agg reads
    {
      int row = tid >> 7, cf = tid & 127;
      float4 v = *(const float4*)(x + ((size_t)(b * Nn + n0 + row)) * Dd + cf * 4);
      *(float4*)(xt + row * 512 + cf * 4) = v;
    }
    __syncthreads();
#pragma unroll
    for (int i = 0; i < 4; ++i) {
      const int n = n0 + i;
      float4 wa = *(const float4*)(wt + n * 68 + kg * 8);
      float4 wb = *(const float4*)(wt + n * 68 + kg * 8 + 4);
      float4 xa = *(const float4*)(xt + i * 512 + cg * 4);
      float4 xb = *(const float4*)(xt + i * 512 + 256 + cg * 4);
      float wv8[8] = {wa.x, wa.y, wa.z, wa.w, wb.x, wb.y, wb.z, wb.w};
      float xv8[8] = {xa.x, xa.y, xa.z, xa.w, xb.x, xb.y, xb.z, xb.w};
#pragma unroll
      for (int kk = 0; kk < 8; ++kk)
#pragma unroll
        for (int e = 0; e < 8; ++e)
          acc[kk][e] += wv8[kk] * xv8[e];
    }
  }
#pragma unroll
  for (int kk = 0; kk < 8; ++kk) {
    size_t base = ((size_t)((p * Bb + b) * Kk + kg * 8 + kk)) * Dd;
    float4 o0 = {acc[kk][0], acc[kk][1], acc[kk][2], acc[kk][3]};
    float4 o1 = {acc[kk][4], acc[kk][5], acc[kk][6], acc[kk][7]};
    *(float4*)(aggP + base + cg * 4) = o0;
    *(float4*)(aggP + base + 256 + cg * 4) = o1;
  }
}

// ---------------------------------------------------------------------------
// K4: per b: v = l2norm(agg_s+agg_d), t = l2norm(words), sim -> leaky -> pools
// ---------------------------------------------------------------------------
__global__ __launch_bounds__(256) void k4_final(
    const float* __restrict__ words, const float* __restrict__ aggP,
    float* __restrict__ outp)
{
  __shared__ __align__(16) float vsm[16 * 512];
  __shared__ float rnv[16];
  __shared__ float colp[4 * 64];
  __shared__ float rowm[40];
  const int tid = threadIdx.x, b = blockIdx.x;
  const int w = tid >> 6, lane = tid & 63;
  const float* a0 = aggP + (size_t)b * Kk * Dd;
  const float* a1 = aggP + ((size_t)(Bb + b)) * Kk * Dd;
  if (tid < 40) rowm[tid] = -1e30f;
  float cm = -1e30f;

  for (int kc = 0; kc < 4; ++kc) {
    __syncthreads();
    for (int idx = tid; idx < 2048; idx += 256) {
      int r = idx >> 7, cf = idx & 127;
      size_t off = ((size_t)(kc * 16 + r)) * Dd + cf * 4;
      float4 u = *(const float4*)(a0 + off);
      float4 v = *(const float4*)(a1 + off);
      float4 s4 = {u.x + v.x, u.y + v.y, u.z + v.z, u.w + v.w};
      *(float4*)(vsm + r * 512 + cf * 4) = s4;
    }
    __syncthreads();
#pragma unroll
    for (int i = 0; i < 4; ++i) {
      int r = w * 4 + i;
      float4 aq = *(const float4*)(vsm + r * 512 + lane * 4);
      float4 bq = *(const float4*)(vsm + r * 512 + 256 + lane * 4);
      float ss = wave_reduce_sum(dot4(aq, aq) + dot4(bq, bq));
      if (lane == 0) rnv[r] = 1.f / fmaxf(sqrtf(ss), 1e-8f);
    }
    __syncthreads();
    for (int i = 0; i < 10; ++i) {
      const int m = w + 4 * i;
      const float* tr = words + ((size_t)(b * Mm + m)) * Dd;
      float4 ta = *(const float4*)(tr + lane * 4);
      float4 tb = *(const float4*)(tr + 256 + lane * 4);
      float ss = wave_reduce_sum(dot4(ta, ta) + dot4(tb, tb));
      float rnt = 1.f / fmaxf(sqrtf(ss), 1e-8f);
      float rmax_loc = -1e30f;
#pragma unroll
      for (int kk = 0; kk < 16; ++kk) {
        float4 va = *(const float4*)(vsm + kk * 512 + lane * 4);
        float4 vb = *(const float4*)(vsm + kk * 512 + 256 + lane * 4);
        float d = wave_reduce_sum(dot4(ta, va) + dot4(tb, vb));
        float s = d * rnt * rnv[kk];
        s = (s >= 0.f) ? s : 0.1f * s;
        rmax_loc = fmaxf(rmax_loc, s);
        if (lane == (kc * 16 + kk)) cm = fmaxf(cm, s);
      }
      if (lane == 0) rowm[m] = fmaxf(rowm[m], rmax_loc);
    }
  }
  colp[w * 64 + lane] = cm;
  __syncthreads();
  if (w == 0) {
    float c2 = fmaxf(fmaxf(colp[lane], colp[64 + lane]),
                     fmaxf(colp[128 + lane], colp[192 + lane]));
    float csum = wave_reduce_sum(c2);
    float rv = (lane < 40) ? rowm[lane] : 0.f;
    float rsum = wave_reduce_sum(rv);
    if (lane == 0) outp[b] = rsum * (1.f / 40.f) + csum * (1.f / 64.f);
  }
}

extern "C" void kernel_launch(void* const* d_in, const int* in_sizes, int n_in,
                              void* d_out, int out_size, void* d_ws, size_t ws_size,
                              hipStream_t stream)
{
  const float* x_s   = (const float*)d_in[0];
  const float* x_d   = (const float*)d_in[1];
  const float* words = (const float*)d_in[2];
  const float* g_s   = (const float*)d_in[3];
  const float* b_s   = (const float*)d_in[4];
  const float* w1_s  = (const float*)d_in[5];
  const float* b1_s  = (const float*)d_in[6];
  const float* w2_s  = (const float*)d_in[7];
  const float* b2_s  = (const float*)d_in[8];
  const float* g_d   = (const float*)d_in[9];
  const float* b_d   = (const float*)d_in[10];
  const float* w1_d  = (const float*)d_in[11];
  const float* b1_d  = (const float*)d_in[12];
  const float* w2_d  = (const float*)d_in[13];
  const float* b2_d  = (const float*)d_in[14];
  const float* scale = (const float*)d_in[15];
  (void)in_sizes; (void)n_in; (void)out_size; (void)ws_size;

  float* logits = (float*)d_ws;
  float* aggP   = (float*)((char*)d_ws + LOGITS_BYTES);

  hipLaunchKernelGGL(k1_logits, dim3(2, 2, 256), dim3(512), 0, stream,
                     x_s, x_d, g_s, b_s, w1_s, b1_s, w2_s, b2_s,
                     g_d, b_d, w1_d, b1_d, w2_d, b2_d, logits);
  hipLaunchKernelGGL(k2_softmax_agg, dim3(2, 256), dim3(512), 0, stream,
                     x_s, x_d, logits, scale, aggP);
  hipLaunchKernelGGL(k4_final, dim3(256), dim3(256), 0, stream,
                     words, aggP, (float*)d_out);
}

// Round 4
// 688.213 us; speedup vs baseline: 10.0376x; 4.8047x over previous
//
#include <hip/hip_runtime.h>
#include <math.h>

// Problem dims
#define Bb 256
#define Nn 196
#define Dd 512
#define Hh 102
#define Kk 64
#define Mm 40

// ws layout: logits [B][2][N][K] f32 = 25,690,112 B ; aggP [2][B][K][D] f32 = 67,108,864 B
#define LOGITS_BYTES 25690112

__device__ __forceinline__ float dot4(const float4 a, const float4 b) {
  return a.x*b.x + a.y*b.y + a.z*b.z + a.w*b.w;
}
__device__ __forceinline__ float4 ld4s(const float* p) { return *(const float4*)p; }
__device__ __forceinline__ float gelu1(float z) {
  return 0.5f * z * (1.f + erff(z * 0.70710678118f));
}

__device__ __forceinline__ float wave_reduce_sum(float v) {
#pragma unroll
  for (int o = 1; o < 64; o <<= 1) v += __shfl_xor(v, o, 64);
  return v;
}

// ---------------------------------------------------------------------------
// K1: per 112-token tile of one (b, path): LN -> gelu(x@w1+b1) -> @w2+b2
// NO indexed local arrays (named float4 accs), unroll-1 K loops: spill-proof.
// ---------------------------------------------------------------------------
__global__ __launch_bounds__(512) void k1_logits(
    const float* __restrict__ x_s, const float* __restrict__ x_d,
    const float* __restrict__ g_s, const float* __restrict__ bb_s,
    const float* __restrict__ w1_s, const float* __restrict__ b1_s,
    const float* __restrict__ w2_s, const float* __restrict__ b2_s,
    const float* __restrict__ g_d, const float* __restrict__ bb_d,
    const float* __restrict__ w1_d, const float* __restrict__ b1_d,
    const float* __restrict__ w2_d, const float* __restrict__ b2_d,
    float* __restrict__ logits)
{
  // phase1: gs(512) bs(512) st(224) xs(112x36) w1t(128x36) = 9888 f
  // phase2: hs(112x108) w2t(32x108) = 15552 f = 62.2 KB (union)
  __shared__ __align__(16) float smem[15552];
  float* gs  = smem;
  float* bs  = smem + 512;
  float* st  = smem + 1024;   // [112][2]
  float* xs  = smem + 1248;   // [112][36]
  float* w1t = smem + 5280;   // [128][36]
  float* hs  = smem;          // [112][108]
  float* w2t = smem + 12096;  // [32][108]

  const int tid = threadIdx.x;
  const int ntile = blockIdx.x, p = blockIdx.y, b = blockIdx.z;
  const int nbase = ntile * 112;
  const float* x  = p ? x_d  : x_s;
  const float* gp = p ? g_d  : g_s;
  const float* bp = p ? bb_d : bb_s;
  const float* w1 = p ? w1_d : w1_s;
  const float* b1 = p ? b1_d : b1_s;
  const float* w2 = p ? w2_d : w2_s;
  const float* b2 = p ? b2_d : b2_s;

  gs[tid] = gp[tid];
  bs[tid] = bp[tid];

  // LN stats: wave per token
  const int wv = tid >> 6, lane = tid & 63;
  for (int i = 0; i < 14; ++i) {
    const int t = wv + 8 * i;
    const int n = nbase + t;
    float s = 0.f, ss = 0.f;
    if (n < Nn) {
      const float* xr = x + ((size_t)(b * Nn + n)) * Dd;
      float4 a = ld4s(xr + lane * 4);
      float4 c = ld4s(xr + 256 + lane * 4);
      s  = a.x + a.y + a.z + a.w + c.x + c.y + c.z + c.w;
      ss = dot4(a, a) + dot4(c, c);
    }
    s = wave_reduce_sum(s); ss = wave_reduce_sum(ss);
    if (lane == 0) {
      float mu  = s * (1.f / 512.f);
      float var = fmaxf(ss * (1.f / 512.f) - mu * mu, 0.f);
      st[2 * t]     = mu;
      st[2 * t + 1] = (n < Nn) ? rsqrtf(var + 1e-5f) : 0.f;
    }
  }
  __syncthreads();

  // h-GEMM: thread (ti 0..15, ji 0..31): t = ti+16l (l<7), j = ji+32m (m: f4 comp)
  const int ti = tid & 15, ji = tid >> 4;
  float4 A0 = {0,0,0,0}, A1 = A0, A2 = A0, A3 = A0, A4 = A0, A5 = A0, A6 = A0;

  for (int ch = 0; ch < 16; ++ch) {
    const int c0 = ch * 32;
    __syncthreads();
    for (int idx = tid; idx < 3264; idx += 512) {
      int cl = idx / 102;
      int j  = idx - cl * 102;
      w1t[j * 36 + cl] = w1[(size_t)(c0 + cl) * Hh + j];
    }
    for (int idx = tid; idx < 936; idx += 512) {
      int j  = 102 + idx / 36;
      int cl = idx - (idx / 36) * 36;
      w1t[j * 36 + cl] = 0.f;
    }
    for (int idx = tid; idx < 896; idx += 512) {
      int t = idx >> 3, cf = idx & 7;
      int n = nbase + t;
      float mu = st[2 * t], rs = st[2 * t + 1];
      float4 v = {0.f, 0.f, 0.f, 0.f};
      if (n < Nn) v = ld4s(x + ((size_t)(b * Nn + n)) * Dd + c0 + cf * 4);
      int c = c0 + cf * 4;
      float4 o;
      o.x = (v.x - mu) * rs * gs[c]     + bs[c];
      o.y = (v.y - mu) * rs * gs[c + 1] + bs[c + 1];
      o.z = (v.z - mu) * rs * gs[c + 2] + bs[c + 2];
      o.w = (v.w - mu) * rs * gs[c + 3] + bs[c + 3];
      *(float4*)(xs + t * 36 + cf * 4) = o;
    }
    __syncthreads();
#pragma unroll 1
    for (int cq = 0; cq < 8; ++cq) {
      const float4 w0 = ld4s(w1t + (ji     ) * 36 + cq * 4);
      const float4 wA = ld4s(w1t + (ji + 32) * 36 + cq * 4);
      const float4 wB = ld4s(w1t + (ji + 64) * 36 + cq * 4);
      const float4 wC = ld4s(w1t + (ji + 96) * 36 + cq * 4);
#define STEP1(A, L) { const float4 xq = ld4s(xs + (ti + 16 * (L)) * 36 + cq * 4); \
      (A).x += dot4(xq, w0); (A).y += dot4(xq, wA); \
      (A).z += dot4(xq, wB); (A).w += dot4(xq, wC); }
      STEP1(A0, 0) STEP1(A1, 1) STEP1(A2, 2) STEP1(A3, 3)
      STEP1(A4, 4) STEP1(A5, 5) STEP1(A6, 6)
#undef STEP1
    }
  }

  // bias + exact gelu -> hs (union flip)
  const float bj0 = b1[ji];
  const float bj1 = b1[ji + 32];
  const float bj2 = b1[ji + 64];
  const float bj3 = (ji + 96 < Hh) ? b1[ji + 96] : 0.f;
  __syncthreads();
#define GW1(A, L) { const int t = ti + 16 * (L); \
  hs[t * 108 + ji]      = gelu1((A).x + bj0); \
  hs[t * 108 + ji + 32] = gelu1((A).y + bj1); \
  hs[t * 108 + ji + 64] = gelu1((A).z + bj2); \
  if (ji + 96 < 104) hs[t * 108 + ji + 96] = gelu1((A).w + bj3); }
  GW1(A0, 0) GW1(A1, 1) GW1(A2, 2) GW1(A3, 3)
  GW1(A4, 4) GW1(A5, 5) GW1(A6, 6)
#undef GW1

  // logits GEMM, two k-halves of 32. thread (ki 0..7, ti2 0..63):
  // k = half*32 + kk*8 + ki, kk = float4 component; t = ti2 + 64*l
  const int ki = tid & 7, ti2 = tid >> 3;
  const int tcl0 = ti2, tcl1 = min(ti2 + 64, 111);
  for (int half = 0; half < 2; ++half) {
    __syncthreads();
    for (int idx = tid; idx < 3264; idx += 512) {
      int j = idx >> 5, ko = idx & 31;
      w2t[ko * 108 + j] = w2[(size_t)j * Kk + half * 32 + ko];
    }
    for (int idx = tid; idx < 192; idx += 512) {
      int ko = idx / 6, jp = 102 + (idx - (idx / 6) * 6);
      w2t[ko * 108 + jp] = 0.f;
    }
    __syncthreads();
    float4 P0 = {0,0,0,0}, P1 = P0;
#pragma unroll 1
    for (int jq = 0; jq < 26; ++jq) {
      const float4 u0 = ld4s(w2t + (ki     ) * 108 + jq * 4);
      const float4 u1 = ld4s(w2t + (ki +  8) * 108 + jq * 4);
      const float4 u2 = ld4s(w2t + (ki + 16) * 108 + jq * 4);
      const float4 u3 = ld4s(w2t + (ki + 24) * 108 + jq * 4);
      const float4 h0 = ld4s(hs + tcl0 * 108 + jq * 4);
      const float4 h1 = ld4s(hs + tcl1 * 108 + jq * 4);
      P0.x += dot4(h0, u0); P0.y += dot4(h0, u1); P0.z += dot4(h0, u2); P0.w += dot4(h0, u3);
      P1.x += dot4(h1, u0); P1.y += dot4(h1, u1); P1.z += dot4(h1, u2); P1.w += dot4(h1, u3);
    }
    {
      const int n0 = nbase + tcl0;
      float* lg = logits + ((size_t)(b * 2 + p) * Nn + n0) * Kk + half * 32 + ki;
      if (n0 < Nn) {
        lg[0]  = P0.x + b2[half * 32 + ki];
        lg[8]  = P0.y + b2[half * 32 + ki + 8];
        lg[16] = P0.z + b2[half * 32 + ki + 16];
        lg[24] = P0.w + b2[half * 32 + ki + 24];
      }
      const int t1 = ti2 + 64;
      const int n1 = nbase + t1;
      if (t1 < 112 && n1 < Nn) {
        float* lg1 = logits + ((size_t)(b * 2 + p) * Nn + n1) * Kk + half * 32 + ki;
        lg1[0]  = P1.x + b2[half * 32 + ki];
        lg1[8]  = P1.y + b2[half * 32 + ki + 8];
        lg1[16] = P1.z + b2[half * 32 + ki + 16];
        lg1[24] = P1.w + b2[half * 32 + ki + 24];
      }
    }
  }
}

// ---------------------------------------------------------------------------
// K2: per (p, b): softmax over n (scale pre-applied), then agg = w @ x
// Named float4 accumulators, unroll-1 loops: spill-proof.
// ---------------------------------------------------------------------------
__global__ __launch_bounds__(512) void k2_softmax_agg(
    const float* __restrict__ x_s, const float* __restrict__ x_d,
    const float* __restrict__ logits, const float* __restrict__ scale,
    float* __restrict__ aggP)
{
  __shared__ __align__(16) float wt[196 * 68];
  __shared__ __align__(16) float xt[4 * 512];
  __shared__ float red[8 * 64];
  __shared__ float mxk[64];
  __shared__ float rsk[64];
  const int tid = threadIdx.x;
  const int p = blockIdx.x, b = blockIdx.y;
  const float* x = p ? x_d : x_s;
  const float sc = scale[0];
  const float* lg = logits + (size_t)(b * 2 + p) * Nn * Kk;
  for (int idx = tid; idx < Nn * Kk; idx += 512) {
    int n = idx >> 6, k = idx & 63;
    wt[n * 68 + k] = lg[idx] * sc;
  }
  __syncthreads();
  const int k = tid & 63, g = tid >> 6;
  float mloc = -1e30f;
  for (int n = g; n < Nn; n += 8) mloc = fmaxf(mloc, wt[n * 68 + k]);
  red[g * 64 + k] = mloc;
  __syncthreads();
  if (g == 0) {
    float mm = red[k];
#pragma unroll
    for (int gg = 1; gg < 8; ++gg) mm = fmaxf(mm, red[gg * 64 + k]);
    mxk[k] = mm;
  }
  __syncthreads();
  const float mk = mxk[k];
  float sloc = 0.f;
  for (int n = g; n < Nn; n += 8) {
    float e = expf(wt[n * 68 + k] - mk);
    wt[n * 68 + k] = e;
    sloc += e;
  }
  red[g * 64 + k] = sloc;
  __syncthreads();
  if (g == 0) {
    float sm = red[k];
#pragma unroll
    for (int gg = 1; gg < 8; ++gg) sm += red[gg * 64 + k];
    rsk[k] = 1.f / sm;
  }
  __syncthreads();
  const float rk = rsk[k];
  for (int n = g; n < Nn; n += 8) wt[n * 68 + k] *= rk;

  // agg: wave kg owns k = kg*8 + kk (kk 0..7); lane cg owns c = cg*4 (+256)
  const int kg = tid >> 6, cg = tid & 63;
  float4 c0a = {0,0,0,0}, c0b = c0a, c1a = c0a, c1b = c0a;
  float4 c2a = c0a, c2b = c0a, c3a = c0a, c3b = c0a;
  float4 c4a = c0a, c4b = c0a, c5a = c0a, c5b = c0a;
  float4 c6a = c0a, c6b = c0a, c7a = c0a, c7b = c0a;

#pragma unroll 1
  for (int nt = 0; nt < 49; ++nt) {
    const int n0 = nt * 4;
    __syncthreads();
    {
      int row = tid >> 7, cf = tid & 127;
      float4 v = ld4s(x + ((size_t)(b * Nn + n0 + row)) * Dd + cf * 4);
      *(float4*)(xt + row * 512 + cf * 4) = v;
    }
    __syncthreads();
#pragma unroll 1
    for (int i = 0; i < 4; ++i) {
      const int n = n0 + i;
      const float4 wa = ld4s(wt + n * 68 + kg * 8);
      const float4 wb = ld4s(wt + n * 68 + kg * 8 + 4);
      const float4 xa = ld4s(xt + i * 512 + cg * 4);
      const float4 xb = ld4s(xt + i * 512 + 256 + cg * 4);
#define KSTEP(W, CA, CB) { \
      (CA).x += (W) * xa.x; (CA).y += (W) * xa.y; (CA).z += (W) * xa.z; (CA).w += (W) * xa.w; \
      (CB).x += (W) * xb.x; (CB).y += (W) * xb.y; (CB).z += (W) * xb.z; (CB).w += (W) * xb.w; }
      KSTEP(wa.x, c0a, c0b) KSTEP(wa.y, c1a, c1b)
      KSTEP(wa.z, c2a, c2b) KSTEP(wa.w, c3a, c3b)
      KSTEP(wb.x, c4a, c4b) KSTEP(wb.y, c5a, c5b)
      KSTEP(wb.z, c6a, c6b) KSTEP(wb.w, c7a, c7b)
#undef KSTEP
    }
  }
#define KOUT(KK, CA, CB) { \
  size_t base = ((size_t)((p * Bb + b) * Kk + kg * 8 + (KK))) * Dd; \
  *(float4*)(aggP + base + cg * 4) = CA; \
  *(float4*)(aggP + base + 256 + cg * 4) = CB; }
  KOUT(0, c0a, c0b) KOUT(1, c1a, c1b) KOUT(2, c2a, c2b) KOUT(3, c3a, c3b)
  KOUT(4, c4a, c4b) KOUT(5, c5a, c5b) KOUT(6, c6a, c6b) KOUT(7, c7a, c7b)
#undef KOUT
}

// ---------------------------------------------------------------------------
// K4: per b: v = l2norm(agg_s+agg_d), t = l2norm(words), sim -> leaky -> pools
// ---------------------------------------------------------------------------
__global__ __launch_bounds__(256) void k4_final(
    const float* __restrict__ words, const float* __restrict__ aggP,
    float* __restrict__ outp)
{
  __shared__ __align__(16) float vsm[16 * 512];
  __shared__ float rnv[16];
  __shared__ float colp[4 * 64];
  __shared__ float rowm[40];
  const int tid = threadIdx.x, b = blockIdx.x;
  const int w = tid >> 6, lane = tid & 63;
  const float* a0 = aggP + (size_t)b * Kk * Dd;
  const float* a1 = aggP + ((size_t)(Bb + b)) * Kk * Dd;
  if (tid < 40) rowm[tid] = -1e30f;
  float cm = -1e30f;

  for (int kc = 0; kc < 4; ++kc) {
    __syncthreads();
    for (int idx = tid; idx < 2048; idx += 256) {
      int r = idx >> 7, cf = idx & 127;
      size_t off = ((size_t)(kc * 16 + r)) * Dd + cf * 4;
      float4 u = ld4s(a0 + off);
      float4 v = ld4s(a1 + off);
      float4 s4 = {u.x + v.x, u.y + v.y, u.z + v.z, u.w + v.w};
      *(float4*)(vsm + r * 512 + cf * 4) = s4;
    }
    __syncthreads();
#pragma unroll
    for (int i = 0; i < 4; ++i) {
      int r = w * 4 + i;
      float4 aq = ld4s(vsm + r * 512 + lane * 4);
      float4 bq = ld4s(vsm + r * 512 + 256 + lane * 4);
      float ss = wave_reduce_sum(dot4(aq, aq) + dot4(bq, bq));
      if (lane == 0) rnv[r] = 1.f / fmaxf(sqrtf(ss), 1e-8f);
    }
    __syncthreads();
    for (int i = 0; i < 10; ++i) {
      const int m = w + 4 * i;
      const float* tr = words + ((size_t)(b * Mm + m)) * Dd;
      float4 ta = ld4s(tr + lane * 4);
      float4 tb = ld4s(tr + 256 + lane * 4);
      float ss = wave_reduce_sum(dot4(ta, ta) + dot4(tb, tb));
      float rnt = 1.f / fmaxf(sqrtf(ss), 1e-8f);
      float rmax_loc = -1e30f;
#pragma unroll 1
      for (int kk = 0; kk < 16; ++kk) {
        float4 va = ld4s(vsm + kk * 512 + lane * 4);
        float4 vb = ld4s(vsm + kk * 512 + 256 + lane * 4);
        float d = wave_reduce_sum(dot4(ta, va) + dot4(tb, vb));
        float s = d * rnt * rnv[kk];
        s = (s >= 0.f) ? s : 0.1f * s;
        rmax_loc = fmaxf(rmax_loc, s);
        if (lane == (kc * 16 + kk)) cm = fmaxf(cm, s);
      }
      if (lane == 0) rowm[m] = fmaxf(rowm[m], rmax_loc);
    }
  }
  colp[w * 64 + lane] = cm;
  __syncthreads();
  if (w == 0) {
    float c2 = fmaxf(fmaxf(colp[lane], colp[64 + lane]),
                     fmaxf(colp[128 + lane], colp[192 + lane]));
    float csum = wave_reduce_sum(c2);
    float rv = (lane < 40) ? rowm[lane] : 0.f;
    float rsum = wave_reduce_sum(rv);
    if (lane == 0) outp[b] = rsum * (1.f / 40.f) + csum * (1.f / 64.f);
  }
}

extern "C" void kernel_launch(void* const* d_in, const int* in_sizes, int n_in,
                              void* d_out, int out_size, void* d_ws, size_t ws_size,
                              hipStream_t stream)
{
  const float* x_s   = (const float*)d_in[0];
  const float* x_d   = (const float*)d_in[1];
  const float* words = (const float*)d_in[2];
  const float* g_s   = (const float*)d_in[3];
  const float* b_s   = (const float*)d_in[4];
  const float* w1_s  = (const float*)d_in[5];
  const float* b1_s  = (const float*)d_in[6];
  const float* w2_s  = (const float*)d_in[7];
  const float* b2_s  = (const float*)d_in[8];
  const float* g_d   = (const float*)d_in[9];
  const float* b_d   = (const float*)d_in[10];
  const float* w1_d  = (const float*)d_in[11];
  const float* b1_d  = (const float*)d_in[12];
  const float* w2_d  = (const float*)d_in[13];
  const float* b2_d  = (const float*)d_in[14];
  const float* scale = (const float*)d_in[15];
  (void)in_sizes; (void)n_in; (void)out_size; (void)ws_size;

  float* logits = (float*)d_ws;
  float* aggP   = (float*)((char*)d_ws + LOGITS_BYTES);

  hipLaunchKernelGGL(k1_logits, dim3(2, 2, 256), dim3(512), 0, stream,
                     x_s, x_d, g_s, b_s, w1_s, b1_s, w2_s, b2_s,
                     g_d, b_d, w1_d, b1_d, w2_d, b2_d, logits);
  hipLaunchKernelGGL(k2_softmax_agg, dim3(2, 256), dim3(512), 0, stream,
                     x_s, x_d, logits, scale, aggP);
  hipLaunchKernelGGL(k4_final, dim3(256), dim3(256), 0, stream,
                     words, aggP, (float*)d_out);
}

// Round 5
// 521.857 us; speedup vs baseline: 13.2374x; 1.3188x over previous
//
#include <hip/hip_runtime.h>
#include <math.h>

// Problem dims
#define Bb 256
#define Nn 196
#define Dd 512
#define Hh 102
#define Kk 64
#define Mm 40

// ws layout: logits [B][2][N][K] f32 = 25,690,112 B ; aggP [2][B][K][D] f32 = 67,108,864 B
#define LOGITS_BYTES 25690112

using short8 = __attribute__((ext_vector_type(8))) short;
using f32x4  = __attribute__((ext_vector_type(4))) float;

__device__ __forceinline__ float dot4(const float4 a, const float4 b) {
  return a.x*b.x + a.y*b.y + a.z*b.z + a.w*b.w;
}
__device__ __forceinline__ float4 ld4s(const float* p) { return *(const float4*)p; }
__device__ __forceinline__ float gelu1(float z) {
  return 0.5f * z * (1.f + erff(z * 0.70710678118f));
}
__device__ __forceinline__ unsigned short bf16hi(float v) {
  return (unsigned short)(__float_as_uint(v) >> 16);
}
__device__ __forceinline__ float hipart(float v) {
  return __uint_as_float(__float_as_uint(v) & 0xffff0000u);
}

__device__ __forceinline__ float wave_reduce_sum(float v) {
#pragma unroll
  for (int o = 1; o < 64; o <<= 1) v += __shfl_xor(v, o, 64);
  return v;
}

// ---------------------------------------------------------------------------
// K1: per 112-token tile of one (b, path): LN -> gelu(x@w1+b1) -> @w2+b2
// h-GEMM via split-bf16 MFMA (hi/lo, 3 products): fp32-grade accuracy at
// matrix-core rate. Logits GEMM stays fp32 VALU (tiny).
// ---------------------------------------------------------------------------
__global__ __launch_bounds__(512) void k1_logits(
    const float* __restrict__ x_s, const float* __restrict__ x_d,
    const float* __restrict__ g_s, const float* __restrict__ bb_s,
    const float* __restrict__ w1_s, const float* __restrict__ b1_s,
    const float* __restrict__ w2_s, const float* __restrict__ b2_s,
    const float* __restrict__ g_d, const float* __restrict__ bb_d,
    const float* __restrict__ w1_d, const float* __restrict__ b1_d,
    const float* __restrict__ w2_d, const float* __restrict__ b2_d,
    float* __restrict__ logits)
{
  // phase1 (floats): gs 512 | bs 512 | st 224 | xh 2240 | xl 2240 | w1h 2560 | w1l 2560
  //   (xh/xl: [112][40] ushort, w1h/w1l: [128][40] ushort; stride 40 bf16 = 80 B,
  //    16B-aligned b128 frags, bank-group 5r mod 8 -> 2 lanes/bank = free)
  // phase2: hs [112][108] f32 (12096) + w2t [32][108] f32 (3456) = 15552 f union
  __shared__ __align__(16) float smem[15552];
  float* gs = smem;
  float* bs = smem + 512;
  float* st = smem + 1024;                       // [112][2]
  unsigned short* xh  = (unsigned short*)(smem + 1248);
  unsigned short* xl  = (unsigned short*)(smem + 1248 + 2240);
  unsigned short* w1h = (unsigned short*)(smem + 1248 + 4480);
  unsigned short* w1l = (unsigned short*)(smem + 1248 + 4480 + 2560);
  float* hs  = smem;                             // [112][108]
  float* w2t = smem + 12096;                     // [32][108]

  const int tid = threadIdx.x;
  const int ntile = blockIdx.x, p = blockIdx.y, b = blockIdx.z;
  const int nbase = ntile * 112;
  const float* x  = p ? x_d  : x_s;
  const float* gp = p ? g_d  : g_s;
  const float* bp = p ? bb_d : bb_s;
  const float* w1 = p ? w1_d : w1_s;
  const float* b1 = p ? b1_d : b1_s;
  const float* w2 = p ? w2_d : w2_s;
  const float* b2 = p ? b2_d : b2_s;

  gs[tid] = gp[tid];
  bs[tid] = bp[tid];

  // LN stats: wave per token
  const int wv = tid >> 6, lane = tid & 63;
  for (int i = 0; i < 14; ++i) {
    const int t = wv + 8 * i;
    const int n = nbase + t;
    float s = 0.f, ss = 0.f;
    if (n < Nn) {
      const float* xr = x + ((size_t)(b * Nn + n)) * Dd;
      float4 a = ld4s(xr + lane * 4);
      float4 c = ld4s(xr + 256 + lane * 4);
      s  = a.x + a.y + a.z + a.w + c.x + c.y + c.z + c.w;
      ss = dot4(a, a) + dot4(c, c);
    }
    s = wave_reduce_sum(s); ss = wave_reduce_sum(ss);
    if (lane == 0) {
      float mu  = s * (1.f / 512.f);
      float var = fmaxf(ss * (1.f / 512.f) - mu * mu, 0.f);
      st[2 * t]     = mu;
      st[2 * t + 1] = (n < Nn) ? rsqrtf(var + 1e-5f) : 0.f;
    }
  }
  __syncthreads();

  // h-GEMM via MFMA. Wave wv owns j-tile jb=16*wv; 7 M-tiles of 16 tokens.
  const int lr = lane & 15, lg = lane >> 4;
  const int jb = wv * 16;
  f32x4 acc[7];
#pragma unroll
  for (int m = 0; m < 7; ++m) acc[m] = (f32x4){0.f, 0.f, 0.f, 0.f};

#pragma unroll 1
  for (int ch = 0; ch < 16; ++ch) {
    const int c0 = ch * 32;
    __syncthreads();
    // stage w1 chunk (32 c x 128 j) transposed + split: w1h/w1l [j][cl]
#pragma unroll 1
    for (int it = 0; it < 8; ++it) {
      int idx = tid + it * 512;
      int cl = idx >> 7, j = idx & 127;
      float v = (j < Hh) ? w1[(size_t)(c0 + cl) * Hh + j] : 0.f;
      unsigned short h = bf16hi(v);
      unsigned short l = bf16hi(v - hipart(v));
      w1h[j * 40 + cl] = h;
      w1l[j * 40 + cl] = l;
    }
    // stage x chunk (112 t x 32 c) with LN applied + split: 8 c per thread
    if (tid < 448) {
      const int t = tid >> 2, q = tid & 3;
      const int n = nbase + t;
      const float mu = st[2 * t], rs = st[2 * t + 1];
      float4 va = {0.f, 0.f, 0.f, 0.f}, vb = va;
      if (n < Nn) {
        const float* xr = x + ((size_t)(b * Nn + n)) * Dd + c0 + q * 8;
        va = ld4s(xr);
        vb = ld4s(xr + 4);
      }
      const int c = c0 + q * 8;
      float o0 = (va.x - mu) * rs * gs[c]     + bs[c];
      float o1 = (va.y - mu) * rs * gs[c + 1] + bs[c + 1];
      float o2 = (va.z - mu) * rs * gs[c + 2] + bs[c + 2];
      float o3 = (va.w - mu) * rs * gs[c + 3] + bs[c + 3];
      float o4 = (vb.x - mu) * rs * gs[c + 4] + bs[c + 4];
      float o5 = (vb.y - mu) * rs * gs[c + 5] + bs[c + 5];
      float o6 = (vb.z - mu) * rs * gs[c + 6] + bs[c + 6];
      float o7 = (vb.w - mu) * rs * gs[c + 7] + bs[c + 7];
      short8 hh, ll;
      hh[0] = (short)bf16hi(o0); ll[0] = (short)bf16hi(o0 - hipart(o0));
      hh[1] = (short)bf16hi(o1); ll[1] = (short)bf16hi(o1 - hipart(o1));
      hh[2] = (short)bf16hi(o2); ll[2] = (short)bf16hi(o2 - hipart(o2));
      hh[3] = (short)bf16hi(o3); ll[3] = (short)bf16hi(o3 - hipart(o3));
      hh[4] = (short)bf16hi(o4); ll[4] = (short)bf16hi(o4 - hipart(o4));
      hh[5] = (short)bf16hi(o5); ll[5] = (short)bf16hi(o5 - hipart(o5));
      hh[6] = (short)bf16hi(o6); ll[6] = (short)bf16hi(o6 - hipart(o6));
      hh[7] = (short)bf16hi(o7); ll[7] = (short)bf16hi(o7 - hipart(o7));
      *(short8*)(xh + t * 40 + q * 8) = hh;
      *(short8*)(xl + t * 40 + q * 8) = ll;
    }
    __syncthreads();
    // MFMA: B frags (w1t col = jb+lr), A frags per M-tile; 3-product split
    short8 bh = *(const short8*)(w1h + (jb + lr) * 40 + lg * 8);
    short8 bl = *(const short8*)(w1l + (jb + lr) * 40 + lg * 8);
#pragma unroll
    for (int m = 0; m < 7; ++m) {
      short8 ahf = *(const short8*)(xh + (m * 16 + lr) * 40 + lg * 8);
      short8 alf = *(const short8*)(xl + (m * 16 + lr) * 40 + lg * 8);
      acc[m] = __builtin_amdgcn_mfma_f32_16x16x32_bf16(ahf, bh, acc[m], 0, 0, 0);
      acc[m] = __builtin_amdgcn_mfma_f32_16x16x32_bf16(ahf, bl, acc[m], 0, 0, 0);
      acc[m] = __builtin_amdgcn_mfma_f32_16x16x32_bf16(alf, bh, acc[m], 0, 0, 0);
    }
  }

  // bias + exact gelu -> hs. C layout: col = jb+lr, row = m*16 + lg*4 + r.
  const int col = jb + lr;
  const float b1v = (col < Hh) ? b1[col] : 0.f;
  __syncthreads();
  if (col < 104) {
#pragma unroll
    for (int m = 0; m < 7; ++m) {
#pragma unroll
      for (int r = 0; r < 4; ++r) {
        const int row = m * 16 + lg * 4 + r;
        hs[row * 108 + col] = gelu1(acc[m][r] + b1v);
      }
    }
  }

  // logits GEMM, two k-halves of 32 (fp32 VALU; w2t reads broadcast).
  const int ki = tid & 7, ti2 = tid >> 3;
  const int tcl0 = ti2, tcl1 = min(ti2 + 64, 111);
  for (int half = 0; half < 2; ++half) {
    __syncthreads();
    for (int idx = tid; idx < 3264; idx += 512) {
      int j = idx >> 5, ko = idx & 31;
      w2t[ko * 108 + j] = w2[(size_t)j * Kk + half * 32 + ko];
    }
    for (int idx = tid; idx < 192; idx += 512) {
      int ko = idx / 6, jp = 102 + (idx - (idx / 6) * 6);
      w2t[ko * 108 + jp] = 0.f;
    }
    __syncthreads();
    float4 P0 = {0,0,0,0}, P1 = P0;
#pragma unroll 1
    for (int jq = 0; jq < 26; ++jq) {
      const float4 u0 = ld4s(w2t + (ki     ) * 108 + jq * 4);
      const float4 u1 = ld4s(w2t + (ki +  8) * 108 + jq * 4);
      const float4 u2 = ld4s(w2t + (ki + 16) * 108 + jq * 4);
      const float4 u3 = ld4s(w2t + (ki + 24) * 108 + jq * 4);
      const float4 h0 = ld4s(hs + tcl0 * 108 + jq * 4);
      const float4 h1 = ld4s(hs + tcl1 * 108 + jq * 4);
      P0.x += dot4(h0, u0); P0.y += dot4(h0, u1); P0.z += dot4(h0, u2); P0.w += dot4(h0, u3);
      P1.x += dot4(h1, u0); P1.y += dot4(h1, u1); P1.z += dot4(h1, u2); P1.w += dot4(h1, u3);
    }
    {
      const int n0 = nbase + tcl0;
      if (n0 < Nn) {
        float* lg = logits + ((size_t)(b * 2 + p) * Nn + n0) * Kk + half * 32 + ki;
        lg[0]  = P0.x + b2[half * 32 + ki];
        lg[8]  = P0.y + b2[half * 32 + ki + 8];
        lg[16] = P0.z + b2[half * 32 + ki + 16];
        lg[24] = P0.w + b2[half * 32 + ki + 24];
      }
      const int t1 = ti2 + 64;
      const int n1 = nbase + t1;
      if (t1 < 112 && n1 < Nn) {
        float* lg1 = logits + ((size_t)(b * 2 + p) * Nn + n1) * Kk + half * 32 + ki;
        lg1[0]  = P1.x + b2[half * 32 + ki];
        lg1[8]  = P1.y + b2[half * 32 + ki + 8];
        lg1[16] = P1.z + b2[half * 32 + ki + 16];
        lg1[24] = P1.w + b2[half * 32 + ki + 24];
      }
    }
  }
}

// ---------------------------------------------------------------------------
// K2: per (p, b): softmax over n (scale pre-applied), then agg = w @ x
// ---------------------------------------------------------------------------
__global__ __launch_bounds__(512) void k2_softmax_agg(
    const float* __restrict__ x_s, const float* __restrict__ x_d,
    const float* __restrict__ logits, const float* __restrict__ scale,
    float* __restrict__ aggP)
{
  __shared__ __align__(16) float wt[196 * 68];
  __shared__ __align__(16) float xt[4 * 512];
  __shared__ float red[8 * 64];
  __shared__ float mxk[64];
  __shared__ float rsk[64];
  const int tid = threadIdx.x;
  const int p = blockIdx.x, b = blockIdx.y;
  const float* x = p ? x_d : x_s;
  const float sc = scale[0];
  const float* lg = logits + (size_t)(b * 2 + p) * Nn * Kk;
  for (int idx = tid; idx < Nn * Kk; idx += 512) {
    int n = idx >> 6, k = idx & 63;
    wt[n * 68 + k] = lg[idx] * sc;
  }
  __syncthreads();
  const int k = tid & 63, g = tid >> 6;
  float mloc = -1e30f;
  for (int n = g; n < Nn; n += 8) mloc = fmaxf(mloc, wt[n * 68 + k]);
  red[g * 64 + k] = mloc;
  __syncthreads();
  if (g == 0) {
    float mm = red[k];
#pragma unroll
    for (int gg = 1; gg < 8; ++gg) mm = fmaxf(mm, red[gg * 64 + k]);
    mxk[k] = mm;
  }
  __syncthreads();
  const float mk = mxk[k];
  float sloc = 0.f;
  for (int n = g; n < Nn; n += 8) {
    float e = expf(wt[n * 68 + k] - mk);
    wt[n * 68 + k] = e;
    sloc += e;
  }
  red[g * 64 + k] = sloc;
  __syncthreads();
  if (g == 0) {
    float sm = red[k];
#pragma unroll
    for (int gg = 1; gg < 8; ++gg) sm += red[gg * 64 + k];
    rsk[k] = 1.f / sm;
  }
  __syncthreads();
  const float rk = rsk[k];
  for (int n = g; n < Nn; n += 8) wt[n * 68 + k] *= rk;

  // agg: wave kg owns k = kg*8 + kk (kk 0..7); lane cg owns c = cg*4 (+256)
  const int kg = tid >> 6, cg = tid & 63;
  float4 c0a = {0,0,0,0}, c0b = c0a, c1a = c0a, c1b = c0a;
  float4 c2a = c0a, c2b = c0a, c3a = c0a, c3b = c0a;
  float4 c4a = c0a, c4b = c0a, c5a = c0a, c5b = c0a;
  float4 c6a = c0a, c6b = c0a, c7a = c0a, c7b = c0a;

#pragma unroll 1
  for (int nt = 0; nt < 49; ++nt) {
    const int n0 = nt * 4;
    __syncthreads();
    {
      int row = tid >> 7, cf = tid & 127;
      float4 v = ld4s(x + ((size_t)(b * Nn + n0 + row)) * Dd + cf * 4);
      *(float4*)(xt + row * 512 + cf * 4) = v;
    }
    __syncthreads();
#pragma unroll 1
    for (int i = 0; i < 4; ++i) {
      const int n = n0 + i;
      const float4 wa = ld4s(wt + n * 68 + kg * 8);
      const float4 wb = ld4s(wt + n * 68 + kg * 8 + 4);
      const float4 xa = ld4s(xt + i * 512 + cg * 4);
      const float4 xb = ld4s(xt + i * 512 + 256 + cg * 4);
#define KSTEP(W, CA, CB) { \
      (CA).x += (W) * xa.x; (CA).y += (W) * xa.y; (CA).z += (W) * xa.z; (CA).w += (W) * xa.w; \
      (CB).x += (W) * xb.x; (CB).y += (W) * xb.y; (CB).z += (W) * xb.z; (CB).w += (W) * xb.w; }
      KSTEP(wa.x, c0a, c0b) KSTEP(wa.y, c1a, c1b)
      KSTEP(wa.z, c2a, c2b) KSTEP(wa.w, c3a, c3b)
      KSTEP(wb.x, c4a, c4b) KSTEP(wb.y, c5a, c5b)
      KSTEP(wb.z, c6a, c6b) KSTEP(wb.w, c7a, c7b)
#undef KSTEP
    }
  }
#define KOUT(KK, CA, CB) { \
  size_t base = ((size_t)((p * Bb + b) * Kk + kg * 8 + (KK))) * Dd; \
  *(float4*)(aggP + base + cg * 4) = CA; \
  *(float4*)(aggP + base + 256 + cg * 4) = CB; }
  KOUT(0, c0a, c0b) KOUT(1, c1a, c1b) KOUT(2, c2a, c2b) KOUT(3, c3a, c3b)
  KOUT(4, c4a, c4b) KOUT(5, c5a, c5b) KOUT(6, c6a, c6b) KOUT(7, c7a, c7b)
#undef KOUT
}

// ---------------------------------------------------------------------------
// K4: per b: v = l2norm(agg_s+agg_d), t = l2norm(words), sim -> leaky -> pools
// ---------------------------------------------------------------------------
__global__ __launch_bounds__(256) void k4_final(
    const float* __restrict__ words, const float* __restrict__ aggP,
    float* __restrict__ outp)
{
  __shared__ __align__(16) float vsm[16 * 512];
  __shared__ float rnv[16];
  __shared__ float colp[4 * 64];
  __shared__ float rowm[40];
  const int tid = threadIdx.x, b = blockIdx.x;
  const int w = tid >> 6, lane = tid & 63;
  const float* a0 = aggP + (size_t)b * Kk * Dd;
  const float* a1 = aggP + ((size_t)(Bb + b)) * Kk * Dd;
  if (tid < 40) rowm[tid] = -1e30f;
  float cm = -1e30f;

  for (int kc = 0; kc < 4; ++kc) {
    __syncthreads();
    for (int idx = tid; idx < 2048; idx += 256) {
      int r = idx >> 7, cf = idx & 127;
      size_t off = ((size_t)(kc * 16 + r)) * Dd + cf * 4;
      float4 u = ld4s(a0 + off);
      float4 v = ld4s(a1 + off);
      float4 s4 = {u.x + v.x, u.y + v.y, u.z + v.z, u.w + v.w};
      *(float4*)(vsm + r * 512 + cf * 4) = s4;
    }
    __syncthreads();
#pragma unroll
    for (int i = 0; i < 4; ++i) {
      int r = w * 4 + i;
      float4 aq = ld4s(vsm + r * 512 + lane * 4);
      float4 bq = ld4s(vsm + r * 512 + 256 + lane * 4);
      float ss = wave_reduce_sum(dot4(aq, aq) + dot4(bq, bq));
      if (lane == 0) rnv[r] = 1.f / fmaxf(sqrtf(ss), 1e-8f);
    }
    __syncthreads();
    for (int i = 0; i < 10; ++i) {
      const int m = w + 4 * i;
      const float* tr = words + ((size_t)(b * Mm + m)) * Dd;
      float4 ta = ld4s(tr + lane * 4);
      float4 tb = ld4s(tr + 256 + lane * 4);
      float ss = wave_reduce_sum(dot4(ta, ta) + dot4(tb, tb));
      float rnt = 1.f / fmaxf(sqrtf(ss), 1e-8f);
      float rmax_loc = -1e30f;
#pragma unroll 1
      for (int kk = 0; kk < 16; ++kk) {
        float4 va = ld4s(vsm + kk * 512 + lane * 4);
        float4 vb = ld4s(vsm + kk * 512 + 256 + lane * 4);
        float d = wave_reduce_sum(dot4(ta, va) + dot4(tb, vb));
        float s = d * rnt * rnv[kk];
        s = (s >= 0.f) ? s : 0.1f * s;
        rmax_loc = fmaxf(rmax_loc, s);
        if (lane == (kc * 16 + kk)) cm = fmaxf(cm, s);
      }
      if (lane == 0) rowm[m] = fmaxf(rowm[m], rmax_loc);
    }
  }
  colp[w * 64 + lane] = cm;
  __syncthreads();
  if (w == 0) {
    float c2 = fmaxf(fmaxf(colp[lane], colp[64 + lane]),
                     fmaxf(colp[128 + lane], colp[192 + lane]));
    float csum = wave_reduce_sum(c2);
    float rv = (lane < 40) ? rowm[lane] : 0.f;
    float rsum = wave_reduce_sum(rv);
    if (lane == 0) outp[b] = rsum * (1.f / 40.f) + csum * (1.f / 64.f);
  }
}

extern "C" void kernel_launch(void* const* d_in, const int* in_sizes, int n_in,
                              void* d_out, int out_size, void* d_ws, size_t ws_size,
                              hipStream_t stream)
{
  const float* x_s   = (const float*)d_in[0];
  const float* x_d   = (const float*)d_in[1];
  const float* words = (const float*)d_in[2];
  const float* g_s   = (const float*)d_in[3];
  const float* b_s   = (const float*)d_in[4];
  const float* w1_s  = (const float*)d_in[5];
  const float* b1_s  = (const float*)d_in[6];
  const float* w2_s  = (const float*)d_in[7];
  const float* b2_s  = (const float*)d_in[8];
  const float* g_d   = (const float*)d_in[9];
  const float* b_d   = (const float*)d_in[10];
  const float* w1_d  = (const float*)d_in[11];
  const float* b1_d  = (const float*)d_in[12];
  const float* w2_d  = (const float*)d_in[13];
  const float* b2_d  = (const float*)d_in[14];
  const float* scale = (const float*)d_in[15];
  (void)in_sizes; (void)n_in; (void)out_size; (void)ws_size;

  float* logits = (float*)d_ws;
  float* aggP   = (float*)((char*)d_ws + LOGITS_BYTES);

  hipLaunchKernelGGL(k1_logits, dim3(2, 2, 256), dim3(512), 0, stream,
                     x_s, x_d, g_s, b_s, w1_s, b1_s, w2_s, b2_s,
                     g_d, b_d, w1_d, b1_d, w2_d, b2_d, logits);
  hipLaunchKernelGGL(k2_softmax_agg, dim3(2, 256), dim3(512), 0, stream,
                     x_s, x_d, logits, scale, aggP);
  hipLaunchKernelGGL(k4_final, dim3(256), dim3(256), 0, stream,
                     words, aggP, (float*)d_out);
}